// Round 14
// baseline (316.593 us; speedup 1.0000x reference)
//
#include <hip/hip_runtime.h>
#include <hip/hip_bf16.h>
#include <hip/hip_fp16.h>
#include <math.h>

#define N_HEADN 100000
#define N_TAILN 100000
#define NEDGE   1600000
#define SLOPE   0.2f

#define NB   196      // buckets: head>>9
#define HPB  512      // heads per bucket
#define BCAP 9216     // bucket capacity (mean 8191, sigma ~90; 9216 = +11 sigma)

// fusedA role ranges
#define FB_K2 1563    // k2 role: 1563 blocks x 64 rows
#define FB_P1 1250    // p1 role: 1250 blocks x 1280 edges
#define FB_K1 6250    // k1 role: 6250 blocks x 16 nodes

static __device__ __forceinline__ float bf2f(__hip_bfloat16 x) { return __bfloat162float(x); }

// f16 source (lo/hi half of packed u32), fp32 multiplier + fp32 accumulate, 1 instr/dim
#define FMA_MIX_LO(acc, pk, q) \
  asm("v_fma_mix_f32 %0, %1, %2, %0 op_sel_hi:[1,0,0]" : "+v"(acc) : "v"(pk), "v"(q))
#define FMA_MIX_HI(acc, pk, q) \
  asm("v_fma_mix_f32 %0, %1, %2, %0 op_sel:[1,0,0] op_sel_hi:[1,0,0]" : "+v"(acc) : "v"(pk), "v"(q))

typedef __attribute__((ext_vector_type(8))) short bfrag;   // 8 bf16 (4 VGPRs)
typedef __attribute__((ext_vector_type(4))) float ffrag;   // 4 fp32 acc

// ---------------- k0m: { W -> bf16 TRANSPOSED } + { wl[128][4], he[8][4] prep } ----------
__global__ __launch_bounds__(256) void k0m(const float* __restrict__ W,
                                           const float* __restrict__ W_e,
                                           const float* __restrict__ a_l,
                                           const float* __restrict__ a_e,
                                           const float* __restrict__ emb,
                                           __hip_bfloat16* __restrict__ WbT,
                                           float* __restrict__ wl,
                                           float* __restrict__ he) {
  const int i = (blockIdx.x * 256 + threadIdx.x) * 4;   // 4 consecutive W elems (same row)
  const int r = i >> 7, c = i & 127;
  const float4 v = *(const float4*)&W[i];
  WbT[(size_t)(c + 0) * 128 + r] = __float2bfloat16(v.x);
  WbT[(size_t)(c + 1) * 128 + r] = __float2bfloat16(v.y);
  WbT[(size_t)(c + 2) * 128 + r] = __float2bfloat16(v.z);
  WbT[(size_t)(c + 3) * 128 + r] = __float2bfloat16(v.w);
  if (blockIdx.x == 0 && threadIdx.x < 128) {
    const int t = threadIdx.x;
    #pragma unroll
    for (int h = 0; h < 4; ++h) {
      float sl = 0.f;
      for (int d = 0; d < 32; ++d)
        sl += W[t * 128 + h * 32 + d] * a_l[h * 32 + d];
      wl[t * 4 + h] = sl;
    }
    if (t < 32) {
      const int et = t >> 2, h = t & 3;
      float acc = 0.f;
      for (int d = 0; d < 32; ++d) {
        float tmp = 0.f;
        for (int f = 0; f < 32; ++f)
          tmp += emb[et * 32 + f] * W_e[f * 128 + h * 32 + d];
        acc += a_e[h * 32 + d] * tmp;
      }
      he[et * 4 + h] = acc;
    }
  }
}

// ---------------- fusedA: role-switched { k2-MFMA | p1-partition | k1-h_l } -------------
// R13 post-mortem: the 35KB LDS arena (k2's sBT tile) was charged to ALL 9063 blocks ->
// 4 blocks/CU, occ 37%, all pipes idle, +1.05M bank conflicts (272B stride). Fix: WbT is
// one 32KB buffer read by every block -> permanently L2-hot, so k2 reads B-fragments
// DIRECTLY from global and the arena shrinks to 1KB (p1 hist 784B / k2 sAr 512B).
__global__ __launch_bounds__(256) void fusedA(
    const float* __restrict__ A,            // tail features (k2)
    const __hip_bfloat16* __restrict__ WbT,
    const float* __restrict__ a_r,
    __half* __restrict__ out,               // h_tail fp16
    float* __restrict__ h_r,
    const int* __restrict__ head_ind,       // p1
    const int* __restrict__ tail_ind,
    const int* __restrict__ etype,
    int* __restrict__ bucketCursor,
    unsigned int* __restrict__ recs,
    const float* __restrict__ feat,         // head features (k1)
    const float* __restrict__ wv,           // wl
    float* __restrict__ o) {                // h_l
  __shared__ __align__(16) char smem[1024];
  const int bid = blockIdx.x;
  const int t = threadIdx.x;

  if (bid < FB_K2) {
    // ================= k2 role: h_tail = tail @ W via MFMA + h_r epilogue ==============
    float* sAr = (float*)smem;                         // 512 B
    if (t < 128) sAr[t] = a_r[t];
    __syncthreads();

    const int w = t >> 6, l = t & 63;
    const int lm = l & 15, kg = l >> 4;
    const int row = bid * 64 + w * 16 + lm;
    const int rowc = row < N_TAILN ? row : N_TAILN - 1;
    const float* __restrict__ Arow = A + (size_t)rowc * 128 + kg * 8;

    ffrag acc[8];
    #pragma unroll
    for (int nt = 0; nt < 8; ++nt) acc[nt] = (ffrag){0.f, 0.f, 0.f, 0.f};

    #pragma unroll
    for (int kc = 0; kc < 4; ++kc) {
      const float4 va = *(const float4*)(Arow + kc * 32);
      const float4 vb = *(const float4*)(Arow + kc * 32 + 4);
      union { unsigned short us[8]; bfrag v; } af;
      __hip_bfloat16 b;
      b = __float2bfloat16(va.x); af.us[0] = *(unsigned short*)&b;
      b = __float2bfloat16(va.y); af.us[1] = *(unsigned short*)&b;
      b = __float2bfloat16(va.z); af.us[2] = *(unsigned short*)&b;
      b = __float2bfloat16(va.w); af.us[3] = *(unsigned short*)&b;
      b = __float2bfloat16(vb.x); af.us[4] = *(unsigned short*)&b;
      b = __float2bfloat16(vb.y); af.us[5] = *(unsigned short*)&b;
      b = __float2bfloat16(vb.z); af.us[6] = *(unsigned short*)&b;
      b = __float2bfloat16(vb.w); af.us[7] = *(unsigned short*)&b;
      const int kb = kc * 32 + kg * 8;
      #pragma unroll
      for (int nt = 0; nt < 8; ++nt) {
        const bfrag bf = *(const bfrag*)&WbT[(size_t)(nt * 16 + lm) * 128 + kb];  // L2-hot
        acc[nt] = __builtin_amdgcn_mfma_f32_16x16x32_bf16(af.v, bf, acc[nt], 0, 0, 0);
      }
    }

    // epilogue h_r: per-head (head = nt>>1) partials, butterfly over the 16-lane row-group
    float ph[4][4];
    #pragma unroll
    for (int hh = 0; hh < 4; ++hh)
      #pragma unroll
      for (int i = 0; i < 4; ++i) ph[hh][i] = 0.f;
    #pragma unroll
    for (int nt = 0; nt < 8; ++nt) {
      const float ar = sAr[nt * 16 + lm];
      #pragma unroll
      for (int i = 0; i < 4; ++i) ph[nt >> 1][i] += acc[nt][i] * ar;
    }
    #pragma unroll
    for (int hh = 0; hh < 4; ++hh)
      #pragma unroll
      for (int i = 0; i < 4; ++i) {
        ph[hh][i] += __shfl_xor(ph[hh][i], 1, 64);
        ph[hh][i] += __shfl_xor(ph[hh][i], 2, 64);
        ph[hh][i] += __shfl_xor(ph[hh][i], 4, 64);
        ph[hh][i] += __shfl_xor(ph[hh][i], 8, 64);
      }
    if (lm == 0) {
      #pragma unroll
      for (int i = 0; i < 4; ++i) {
        const int rr = bid * 64 + w * 16 + kg * 4 + i;
        if (rr < N_TAILN)
          *(float4*)&h_r[(size_t)rr * 4] = make_float4(ph[0][i], ph[1][i], ph[2][i], ph[3][i]);
      }
    }

    // C store (fp16): lane holds D rows kg*4+i, col lm of each 16-col tile
    #pragma unroll
    for (int i = 0; i < 4; ++i) {
      const int rr = bid * 64 + w * 16 + kg * 4 + i;
      if (rr < N_TAILN) {
        __half* orow = out + (size_t)rr * 128 + lm;
        #pragma unroll
        for (int nt = 0; nt < 8; ++nt)
          orow[nt * 16] = __float2half(acc[nt][i]);
      }
    }

  } else if (bid < FB_K2 + FB_P1) {
    // ================= p1 role: partition edges into 196 head-buckets ==================
    int* hist = (int*)smem;                            // 784 B
    for (int i = t; i < NB; i += 256) hist[i] = 0;
    __syncthreads();
    const int e0 = (bid - FB_K2) * 1280;               // 1250 blocks x 1280 = 1.6M
    int h[5];
    #pragma unroll
    for (int i = 0; i < 5; ++i) {
      h[i] = head_ind[e0 + i * 256 + t];
      atomicAdd(&hist[h[i] >> 9], 1);
    }
    __syncthreads();
    for (int i = t; i < NB; i += 256) {
      const int c = hist[i];
      hist[i] = (c > 0) ? atomicAdd(&bucketCursor[i], c) : 0;  // hist becomes running cursor
    }
    __syncthreads();
    #pragma unroll
    for (int i = 0; i < 5; ++i) {
      const int e = e0 + i * 256 + t;
      const int hi = h[i];
      const int b = hi >> 9;
      const int pos = atomicAdd(&hist[b], 1);
      recs[b * BCAP + pos] = (unsigned)tail_ind[e] | ((unsigned)etype[e] << 17)
                           | ((unsigned)(hi & 511) << 20);
    }

  } else {
    // ================= k1 role: h_l = head @ wl (16-lane group per node) ===============
    const int gid = (bid - FB_K2 - FB_P1) * 256 + t;   // 6250 blocks -> 100000 nodes
    const int node = gid >> 4, li = gid & 15;
    const float4* row = (const float4*)(feat + (size_t)node * 128 + li * 8);
    const float4 x0 = row[0], x1 = row[1];
    const float* w = wv + li * 32;
    float p0 = 0.f, p1 = 0.f, p2 = 0.f, p3 = 0.f;
    const float xs[8] = {x0.x, x0.y, x0.z, x0.w, x1.x, x1.y, x1.z, x1.w};
    #pragma unroll
    for (int j = 0; j < 8; ++j) {
      const float4 wj = *(const float4*)&w[j * 4];
      p0 += xs[j] * wj.x;
      p1 += xs[j] * wj.y;
      p2 += xs[j] * wj.z;
      p3 += xs[j] * wj.w;
    }
    #pragma unroll
    for (int m = 8; m; m >>= 1) {
      p0 += __shfl_xor(p0, m, 64);
      p1 += __shfl_xor(p1, m, 64);
      p2 += __shfl_xor(p2, m, 64);
      p3 += __shfl_xor(p3, m, 64);
    }
    if (li == 0) *(float4*)(o + (size_t)node * 4) = make_float4(p0, p1, p2, p3);
  }
}

// ---------------- p23: fused {per-head CSR offsets} + {bucket -> CSR scatter} ----------
__global__ __launch_bounds__(1024) void p23(const unsigned int* __restrict__ recs,
                                            const int* __restrict__ bucketCursor,
                                            int* __restrict__ off,
                                            int* __restrict__ pt) {
  __shared__ int cur[HPB];
  __shared__ int red[256];
  const int b = blockIdx.x, t = threadIdx.x;
  if (t < 256) red[t] = (t < b) ? bucketCursor[t] : 0;   // b <= 195 < 256
  if (t < HPB) cur[t] = 0;
  __syncthreads();
  for (int st = 128; st; st >>= 1) {                     // bstart = sum of earlier buckets
    if (t < st) red[t] += red[t + st];
    __syncthreads();
  }
  const int bstart = red[0];
  const int cnt = bucketCursor[b];
  const unsigned int* __restrict__ rb = recs + (size_t)b * BCAP;
  for (int i = t; i < cnt; i += 1024)
    atomicAdd(&cur[rb[i] >> 20], 1);
  __syncthreads();
  const int orig = (t < HPB) ? cur[t] : 0;
  for (int st = 1; st < HPB; st <<= 1) {                 // Hillis-Steele inclusive scan
    int v = 0;
    if (t < HPB && t >= st) v = cur[t - st];
    __syncthreads();
    if (t < HPB) cur[t] += v;
    __syncthreads();
  }
  const int h0 = b * HPB;
  if (t < HPB) {
    const int excl = bstart + cur[t] - orig;             // exclusive prefix
    cur[t] = excl;                                       // becomes scatter cursor
    if (h0 + t < N_HEADN) off[h0 + t] = excl;
  }
  if (b == NB - 1 && t == 0) off[N_HEADN] = NEDGE;
  __syncthreads();
  for (int i = t; i < cnt; i += 1024) {
    const unsigned r = rb[i];
    const int pos = atomicAdd(&cur[r >> 20], 1);
    pt[pos] = (int)(r & 0xFFFFFu);                       // ti | et<<17
  }
}

// ---------------- k4: 16-lane groups, CHUNK=32 (2 edges/lane), fp16 + v_fma_mix --------
// R13: measured good (dropped out of top-5, < 78us). No launch-bounds pin (R3 spill).
__global__ __launch_bounds__(256) void k4_agg(const int* __restrict__ off,
                                              const int* __restrict__ pt,
                                              const float* __restrict__ h_l,
                                              const float* __restrict__ h_r,
                                              const float* __restrict__ he,
                                              const __half* __restrict__ h_tail,
                                              float* __restrict__ out) {
  __shared__ __align__(16) float sw[4][4][136];  // 32 slots x4 + pad; group stride 136
  __shared__ int sti[4][4][36];                  // 32 row byte-offsets + pad
  __shared__ __align__(16) float4 she4[8];
  const int wid = threadIdx.x >> 6;
  const int lane = threadIdx.x & 63;
  const int g = lane >> 4, li = lane & 15;
  if (threadIdx.x < 8) she4[threadIdx.x] = ((const float4*)he)[threadIdx.x];
  __syncthreads();                               // only block barrier: she4 visibility
  const int n = blockIdx.x * 16 + wid * 4 + g;   // grid exact: 6250*16
  const int s = off[n], e = off[n + 1];
  const int nch = (e - s + 31) >> 5;
  const float4 hl = *(const float4*)(h_l + (size_t)n * 4);
  const int h = li >> 2;
  const unsigned dby = (unsigned)li * 16u;       // byte offset of lane's 8 dims (fp16)
  float m0 = -1e30f, m1 = -1e30f, m2 = -1e30f, m3 = -1e30f;
  float s0 = 0.f, s1 = 0.f, s2 = 0.f, s3 = 0.f;
  float acc[8];
  #pragma unroll
  for (int d = 0; d < 8; ++d) acc[d] = 0.f;
  float* __restrict__ swg = &sw[wid][g][0];
  int* __restrict__ stig = &sti[wid][g][0];
  const char* __restrict__ htb = (const char*)h_tail;
  for (int c = 0; c < nch; ++c) {
    const int base = s + (c << 5);
    const int rem = min(32, e - base);
    // edge A = base+li, edge B = base+16+li
    float a0 = -1e30f, a1 = -1e30f, a2 = -1e30f, a3 = -1e30f;
    float b0 = -1e30f, b1 = -1e30f, b2 = -1e30f, b3 = -1e30f;
    if (li < rem) {
      const int pk = pt[base + li];
      const unsigned ti = (unsigned)pk & 0x1FFFFu;
      const float4 hr = *(const float4*)((const char*)h_r + (ti << 4));
      const float4 hv = she4[(pk >> 17) & 7];
      a0 = hl.x + hr.x + hv.x;
      a1 = hl.y + hr.y + hv.y;
      a2 = hl.z + hr.z + hv.z;
      a3 = hl.w + hr.w + hv.w;
      a0 = fmaxf(a0, SLOPE * a0);                // leaky relu (slope<1)
      a1 = fmaxf(a1, SLOPE * a1);
      a2 = fmaxf(a2, SLOPE * a2);
      a3 = fmaxf(a3, SLOPE * a3);
      stig[li] = (int)(ti << 8);                 // h_tail row byte offset (256 B/row)
    }
    if (li + 16 < rem) {
      const int pk = pt[base + 16 + li];
      const unsigned ti = (unsigned)pk & 0x1FFFFu;
      const float4 hr = *(const float4*)((const char*)h_r + (ti << 4));
      const float4 hv = she4[(pk >> 17) & 7];
      b0 = hl.x + hr.x + hv.x;
      b1 = hl.y + hr.y + hv.y;
      b2 = hl.z + hr.z + hv.z;
      b3 = hl.w + hr.w + hv.w;
      b0 = fmaxf(b0, SLOPE * b0);
      b1 = fmaxf(b1, SLOPE * b1);
      b2 = fmaxf(b2, SLOPE * b2);
      b3 = fmaxf(b3, SLOPE * b3);
      stig[li + 16] = (int)(ti << 8);
    }
    float c0 = fmaxf(a0, b0), c1 = fmaxf(a1, b1);
    float c2 = fmaxf(a2, b2), c3 = fmaxf(a3, b3);
    #pragma unroll
    for (int msk = 8; msk; msk >>= 1) {          // width-16 max trees (32 edges)
      c0 = fmaxf(c0, __shfl_xor(c0, msk, 64));
      c1 = fmaxf(c1, __shfl_xor(c1, msk, 64));
      c2 = fmaxf(c2, __shfl_xor(c2, msk, 64));
      c3 = fmaxf(c3, __shfl_xor(c3, msk, 64));
    }
    const float nm0 = fmaxf(m0, c0), nm1 = fmaxf(m1, c1);
    const float nm2 = fmaxf(m2, c2), nm3 = fmaxf(m3, c3);
    const float e0 = __expf(m0 - nm0), e1 = __expf(m1 - nm1);
    const float e2 = __expf(m2 - nm2), e3 = __expf(m3 - nm3);
    const float wa0 = __expf(a0 - nm0), wa1 = __expf(a1 - nm1);
    const float wa2 = __expf(a2 - nm2), wa3 = __expf(a3 - nm3);
    const float wb0 = __expf(b0 - nm0), wb1 = __expf(b1 - nm1);
    const float wb2 = __expf(b2 - nm2), wb3 = __expf(b3 - nm3);
    float t0 = wa0 + wb0, t1 = wa1 + wb1;
    float t2 = wa2 + wb2, t3 = wa3 + wb3;
    #pragma unroll
    for (int msk = 8; msk; msk >>= 1) {          // width-16 sum trees (32 edges)
      t0 += __shfl_xor(t0, msk, 64);
      t1 += __shfl_xor(t1, msk, 64);
      t2 += __shfl_xor(t2, msk, 64);
      t3 += __shfl_xor(t3, msk, 64);
    }
    s0 = s0 * e0 + t0; s1 = s1 * e1 + t1;
    s2 = s2 * e2 + t2; s3 = s3 * e3 + t3;
    m0 = nm0; m1 = nm1; m2 = nm2; m3 = nm3;
    *(float4*)&swg[li * 4] = make_float4(wa0, wa1, wa2, wa3);        // 0 for li >= rem
    *(float4*)&swg[(li + 16) * 4] = make_float4(wb0, wb1, wb2, wb3); // 0 for li+16 >= rem
    const float sc = (h == 0) ? e0 : (h == 1) ? e1 : (h == 2) ? e2 : e3;
    #pragma unroll
    for (int d = 0; d < 8; ++d) acc[d] *= sc;
    __builtin_amdgcn_wave_barrier();
    int j = 0;
    for (; j + 4 <= rem; j += 4) {
      const int o0 = stig[j], o1 = stig[j + 1], o2 = stig[j + 2], o3 = stig[j + 3];
      const float q0 = swg[(j + 0) * 4 + h];
      const float q1 = swg[(j + 1) * 4 + h];
      const float q2 = swg[(j + 2) * 4 + h];
      const float q3 = swg[(j + 3) * 4 + h];
      const uint4 v0 = *(const uint4*)(htb + (unsigned)o0 + dby);
      const uint4 v1 = *(const uint4*)(htb + (unsigned)o1 + dby);
      const uint4 v2 = *(const uint4*)(htb + (unsigned)o2 + dby);
      const uint4 v3 = *(const uint4*)(htb + (unsigned)o3 + dby);
      FMA_MIX_LO(acc[0], v0.x, q0); FMA_MIX_HI(acc[1], v0.x, q0);
      FMA_MIX_LO(acc[2], v0.y, q0); FMA_MIX_HI(acc[3], v0.y, q0);
      FMA_MIX_LO(acc[4], v0.z, q0); FMA_MIX_HI(acc[5], v0.z, q0);
      FMA_MIX_LO(acc[6], v0.w, q0); FMA_MIX_HI(acc[7], v0.w, q0);
      FMA_MIX_LO(acc[0], v1.x, q1); FMA_MIX_HI(acc[1], v1.x, q1);
      FMA_MIX_LO(acc[2], v1.y, q1); FMA_MIX_HI(acc[3], v1.y, q1);
      FMA_MIX_LO(acc[4], v1.z, q1); FMA_MIX_HI(acc[5], v1.z, q1);
      FMA_MIX_LO(acc[6], v1.w, q1); FMA_MIX_HI(acc[7], v1.w, q1);
      FMA_MIX_LO(acc[0], v2.x, q2); FMA_MIX_HI(acc[1], v2.x, q2);
      FMA_MIX_LO(acc[2], v2.y, q2); FMA_MIX_HI(acc[3], v2.y, q2);
      FMA_MIX_LO(acc[4], v2.z, q2); FMA_MIX_HI(acc[5], v2.z, q2);
      FMA_MIX_LO(acc[6], v2.w, q2); FMA_MIX_HI(acc[7], v2.w, q2);
      FMA_MIX_LO(acc[0], v3.x, q3); FMA_MIX_HI(acc[1], v3.x, q3);
      FMA_MIX_LO(acc[2], v3.y, q3); FMA_MIX_HI(acc[3], v3.y, q3);
      FMA_MIX_LO(acc[4], v3.z, q3); FMA_MIX_HI(acc[5], v3.z, q3);
      FMA_MIX_LO(acc[6], v3.w, q3); FMA_MIX_HI(acc[7], v3.w, q3);
    }
    for (; j < rem; ++j) {
      const int o = stig[j];
      const float q = swg[j * 4 + h];
      const uint4 v = *(const uint4*)(htb + (unsigned)o + dby);
      FMA_MIX_LO(acc[0], v.x, q); FMA_MIX_HI(acc[1], v.x, q);
      FMA_MIX_LO(acc[2], v.y, q); FMA_MIX_HI(acc[3], v.y, q);
      FMA_MIX_LO(acc[4], v.z, q); FMA_MIX_HI(acc[5], v.z, q);
      FMA_MIX_LO(acc[6], v.w, q); FMA_MIX_HI(acc[7], v.w, q);
    }
    __builtin_amdgcn_wave_barrier();
  }
  const float denom = (h == 0) ? s0 : (h == 1) ? s1 : (h == 2) ? s2 : s3;
  const float inv = denom > 0.f ? 1.f / denom : 0.f;
  float o[8];
  #pragma unroll
  for (int d = 0; d < 8; ++d) {
    const float v = acc[d] * inv;
    o[d] = v > 0.f ? v : expm1f(v);
  }
  float* op = out + (size_t)n * 128 + li * 8;
  *(float4*)op = make_float4(o[0], o[1], o[2], o[3]);
  *(float4*)(op + 4) = make_float4(o[4], o[5], o[6], o[7]);
}

extern "C" void kernel_launch(void* const* d_in, const int* in_sizes, int n_in,
                              void* d_out, int out_size, void* d_ws, size_t ws_size,
                              hipStream_t stream) {
  const float* head = (const float*)d_in[0];
  const float* tail = (const float*)d_in[1];
  const int* elist  = (const int*)d_in[2];
  const int* etype  = (const int*)d_in[3];
  const float* W    = (const float*)d_in[4];
  const float* W_e  = (const float*)d_in[5];
  const float* a_l  = (const float*)d_in[6];
  const float* a_r  = (const float*)d_in[7];
  const float* a_e  = (const float*)d_in[8];
  const float* emb  = (const float*)d_in[9];
  const int* head_ind = elist;
  const int* tail_ind = elist + NEDGE;
  (void)in_sizes; (void)n_in; (void)out_size; (void)ws_size;

  char* p = (char*)d_ws;
  size_t o = 0;
  auto carve = [&](size_t bytes) {
    char* r = p + o;
    o += (bytes + 255) & ~(size_t)255;
    return r;
  };
  // total ~42.6 MB
  __half* h_tail = (__half*)carve((size_t)N_TAILN * 128 * 2);                   // 25.6 MB
  int*   pt     = (int*)   carve((size_t)NEDGE * 4);                            // 6.4 MB
  unsigned int* recs = (unsigned int*)carve((size_t)NB * BCAP * 4);             // 7.2 MB
  float* h_l    = (float*) carve((size_t)N_HEADN * 4 * 4);                      // 1.6 MB
  float* h_r    = (float*) carve((size_t)N_TAILN * 4 * 4);                      // 1.6 MB
  int*   off    = (int*)   carve((size_t)(N_HEADN + 1) * 4);                    // 0.4 MB
  int*   bucketCursor = (int*)carve(NB * 4);
  float* wl     = (float*) carve(128 * 4 * 4);
  float* he     = (float*) carve(8 * 4 * 4);
  __hip_bfloat16* WbT = (__hip_bfloat16*)carve(16384 * 2);                      // 32 KB

  hipMemsetAsync(bucketCursor, 0, NB * sizeof(int), stream);
  k0m<<<16, 256, 0, stream>>>(W, W_e, a_l, a_e, emb, WbT, wl, he);
  fusedA<<<FB_K2 + FB_P1 + FB_K1, 256, 0, stream>>>(
      tail, WbT, a_r, h_tail, h_r,
      head_ind, tail_ind, etype, bucketCursor, recs,
      head, wl, h_l);
  p23<<<NB, 1024, 0, stream>>>(recs, bucketCursor, off, pt);
  k4_agg<<<N_HEADN / 16, 256, 0, stream>>>(off, pt, h_l, h_r, he, h_tail, (float*)d_out);
}

// Round 17
// 309.193 us; speedup vs baseline: 1.0239x; 1.0239x over previous
//
#include <hip/hip_runtime.h>
#include <hip/hip_bf16.h>
#include <hip/hip_fp16.h>
#include <math.h>

#define N_HEADN 100000
#define N_TAILN 100000
#define NEDGE   1600000
#define SLOPE   0.2f

#define NB   196      // buckets: head>>9
#define HPB  512      // heads per bucket
#define BCAP 9216     // bucket capacity (mean 8191, sigma ~90; 9216 = +11 sigma)

// fusedA role ranges
#define FB_K2 1563    // k2 role: 1563 blocks x 64 rows
#define FB_P1 1250    // p1 role: 1250 blocks x 1280 edges
#define FB_K1 6250    // k1 role: 6250 blocks x 16 nodes

static __device__ __forceinline__ float bf2f(__hip_bfloat16 x) { return __bfloat162float(x); }

// f16 source (lo/hi half of packed u32), fp32 multiplier + fp32 accumulate, 1 instr/dim
#define FMA_MIX_LO(acc, pk, q) \
  asm("v_fma_mix_f32 %0, %1, %2, %0 op_sel_hi:[1,0,0]" : "+v"(acc) : "v"(pk), "v"(q))
#define FMA_MIX_HI(acc, pk, q) \
  asm("v_fma_mix_f32 %0, %1, %2, %0 op_sel:[1,0,0] op_sel_hi:[1,0,0]" : "+v"(acc) : "v"(pk), "v"(q))

typedef __attribute__((ext_vector_type(8))) short bfrag;   // 8 bf16 (4 VGPRs)
typedef __attribute__((ext_vector_type(4))) float ffrag;   // 4 fp32 acc

// ---------------- k0m: { W -> bf16 TRANSPOSED } + { wl[128][4], he[8][4] prep } ----------
__global__ __launch_bounds__(256) void k0m(const float* __restrict__ W,
                                           const float* __restrict__ W_e,
                                           const float* __restrict__ a_l,
                                           const float* __restrict__ a_e,
                                           const float* __restrict__ emb,
                                           __hip_bfloat16* __restrict__ WbT,
                                           float* __restrict__ wl,
                                           float* __restrict__ he) {
  const int i = (blockIdx.x * 256 + threadIdx.x) * 4;   // 4 consecutive W elems (same row)
  const int r = i >> 7, c = i & 127;
  const float4 v = *(const float4*)&W[i];
  WbT[(size_t)(c + 0) * 128 + r] = __float2bfloat16(v.x);
  WbT[(size_t)(c + 1) * 128 + r] = __float2bfloat16(v.y);
  WbT[(size_t)(c + 2) * 128 + r] = __float2bfloat16(v.z);
  WbT[(size_t)(c + 3) * 128 + r] = __float2bfloat16(v.w);
  if (blockIdx.x == 0 && threadIdx.x < 128) {
    const int t = threadIdx.x;
    #pragma unroll
    for (int h = 0; h < 4; ++h) {
      float sl = 0.f;
      for (int d = 0; d < 32; ++d)
        sl += W[t * 128 + h * 32 + d] * a_l[h * 32 + d];
      wl[t * 4 + h] = sl;
    }
    if (t < 32) {
      const int et = t >> 2, h = t & 3;
      float acc = 0.f;
      for (int d = 0; d < 32; ++d) {
        float tmp = 0.f;
        for (int f = 0; f < 32; ++f)
          tmp += emb[et * 32 + f] * W_e[f * 128 + h * 32 + d];
        acc += a_e[h * 32 + d] * tmp;
      }
      he[et * 4 + h] = acc;
    }
  }
}

// ---------------- fusedA: role-switched { k2-MFMA | p1-partition | k1-h_l } -------------
// R13: 35KB arena -> 4 blocks/CU for ALL 9063 blocks (occ 37%, all pipes idle).
// R14: dropping LDS staging for direct-global B regressed (latency in the MFMA chain).
// R15 fix: HALF-TILE staging — stage 64 W-columns at a time in sBT[64][132] (two
// stage->compute phases). LDS 35.3KB -> 17.4KB => 8 blocks/CU (thread-capped) for every
// role; stride 132 (66 words = 2 mod 32) makes the 16-row b128 reads <=2-way (free).
__global__ __launch_bounds__(256) void fusedA(
    const float* __restrict__ A,            // tail features (k2)
    const __hip_bfloat16* __restrict__ WbT,
    const float* __restrict__ a_r,
    __half* __restrict__ out,               // h_tail fp16
    float* __restrict__ h_r,
    const int* __restrict__ head_ind,       // p1
    const int* __restrict__ tail_ind,
    const int* __restrict__ etype,
    int* __restrict__ bucketCursor,
    unsigned int* __restrict__ recs,
    const float* __restrict__ feat,         // head features (k1)
    const float* __restrict__ wv,           // wl
    float* __restrict__ o) {                // h_l
  __shared__ __align__(16) char smem[512 + 64 * 132 * 2];   // 17408 B
  const int bid = blockIdx.x;
  const int t = threadIdx.x;

  if (bid < FB_K2) {
    // ================= k2 role: h_tail = tail @ W via MFMA + h_r epilogue ==============
    float* sAr = (float*)smem;                         // 512 B
    __hip_bfloat16* sBT = (__hip_bfloat16*)(smem + 512);  // [64 cols][132], 2 halves
    if (t < 128) sAr[t] = a_r[t];

    const int w = t >> 6, l = t & 63;
    const int lm = l & 15, kg = l >> 4;
    const int row = bid * 64 + w * 16 + lm;
    const int rowc = row < N_TAILN ? row : N_TAILN - 1;
    const float* __restrict__ Arow = A + (size_t)rowc * 128 + kg * 8;

    ffrag acc[8];
    #pragma unroll
    for (int nt = 0; nt < 8; ++nt) acc[nt] = (ffrag){0.f, 0.f, 0.f, 0.f};

    const uint4* src4 = (const uint4*)WbT;             // 16B chunks, 16 per column
    #pragma unroll
    for (int half = 0; half < 2; ++half) {
      if (half) __syncthreads();                       // drain half-0 readers
      #pragma unroll
      for (int it = 0; it < 4; ++it) {
        const int i = it * 256 + t;                    // 1024 chunks = 64 cols x 16
        const int c = i >> 4, ch = i & 15;
        *(uint4*)&sBT[c * 132 + ch * 8] = src4[(half * 64 + c) * 16 + ch];
      }
      __syncthreads();
      #pragma unroll
      for (int kc = 0; kc < 4; ++kc) {
        const float4 va = *(const float4*)(Arow + kc * 32);      // L1-hot on half 1
        const float4 vb = *(const float4*)(Arow + kc * 32 + 4);
        union { unsigned short us[8]; bfrag v; } af;
        __hip_bfloat16 b;
        b = __float2bfloat16(va.x); af.us[0] = *(unsigned short*)&b;
        b = __float2bfloat16(va.y); af.us[1] = *(unsigned short*)&b;
        b = __float2bfloat16(va.z); af.us[2] = *(unsigned short*)&b;
        b = __float2bfloat16(va.w); af.us[3] = *(unsigned short*)&b;
        b = __float2bfloat16(vb.x); af.us[4] = *(unsigned short*)&b;
        b = __float2bfloat16(vb.y); af.us[5] = *(unsigned short*)&b;
        b = __float2bfloat16(vb.z); af.us[6] = *(unsigned short*)&b;
        b = __float2bfloat16(vb.w); af.us[7] = *(unsigned short*)&b;
        const int kb = kc * 32 + kg * 8;
        #pragma unroll
        for (int ntl = 0; ntl < 4; ++ntl) {
          const bfrag bf = *(const bfrag*)&sBT[(ntl * 16 + lm) * 132 + kb];
          acc[half * 4 + ntl] =
              __builtin_amdgcn_mfma_f32_16x16x32_bf16(af.v, bf, acc[half * 4 + ntl], 0, 0, 0);
        }
      }
    }

    // epilogue h_r: per-head (head = nt>>1) partials, butterfly over the 16-lane row-group
    float ph[4][4];
    #pragma unroll
    for (int hh = 0; hh < 4; ++hh)
      #pragma unroll
      for (int i = 0; i < 4; ++i) ph[hh][i] = 0.f;
    #pragma unroll
    for (int nt = 0; nt < 8; ++nt) {
      const float ar = sAr[nt * 16 + lm];
      #pragma unroll
      for (int i = 0; i < 4; ++i) ph[nt >> 1][i] += acc[nt][i] * ar;
    }
    #pragma unroll
    for (int hh = 0; hh < 4; ++hh)
      #pragma unroll
      for (int i = 0; i < 4; ++i) {
        ph[hh][i] += __shfl_xor(ph[hh][i], 1, 64);
        ph[hh][i] += __shfl_xor(ph[hh][i], 2, 64);
        ph[hh][i] += __shfl_xor(ph[hh][i], 4, 64);
        ph[hh][i] += __shfl_xor(ph[hh][i], 8, 64);
      }
    if (lm == 0) {
      #pragma unroll
      for (int i = 0; i < 4; ++i) {
        const int rr = bid * 64 + w * 16 + kg * 4 + i;
        if (rr < N_TAILN)
          *(float4*)&h_r[(size_t)rr * 4] = make_float4(ph[0][i], ph[1][i], ph[2][i], ph[3][i]);
      }
    }

    // C store (fp16): lane holds D rows kg*4+i, col lm of each 16-col tile
    #pragma unroll
    for (int i = 0; i < 4; ++i) {
      const int rr = bid * 64 + w * 16 + kg * 4 + i;
      if (rr < N_TAILN) {
        __half* orow = out + (size_t)rr * 128 + lm;
        #pragma unroll
        for (int nt = 0; nt < 8; ++nt)
          orow[nt * 16] = __float2half(acc[nt][i]);
      }
    }

  } else if (bid < FB_K2 + FB_P1) {
    // ================= p1 role: partition edges into 196 head-buckets ==================
    int* hist = (int*)smem;                            // 784 B
    for (int i = t; i < NB; i += 256) hist[i] = 0;
    __syncthreads();
    const int e0 = (bid - FB_K2) * 1280;               // 1250 blocks x 1280 = 1.6M
    int h[5];
    #pragma unroll
    for (int i = 0; i < 5; ++i) {
      h[i] = head_ind[e0 + i * 256 + t];
      atomicAdd(&hist[h[i] >> 9], 1);
    }
    __syncthreads();
    for (int i = t; i < NB; i += 256) {
      const int c = hist[i];
      hist[i] = (c > 0) ? atomicAdd(&bucketCursor[i], c) : 0;  // hist becomes running cursor
    }
    __syncthreads();
    #pragma unroll
    for (int i = 0; i < 5; ++i) {
      const int e = e0 + i * 256 + t;
      const int hi = h[i];
      const int b = hi >> 9;
      const int pos = atomicAdd(&hist[b], 1);
      recs[b * BCAP + pos] = (unsigned)tail_ind[e] | ((unsigned)etype[e] << 17)
                           | ((unsigned)(hi & 511) << 20);
    }

  } else {
    // ================= k1 role: h_l = head @ wl (16-lane group per node) ===============
    const int gid = (bid - FB_K2 - FB_P1) * 256 + t;   // 6250 blocks -> 100000 nodes
    const int node = gid >> 4, li = gid & 15;
    const float4* row = (const float4*)(feat + (size_t)node * 128 + li * 8);
    const float4 x0 = row[0], x1 = row[1];
    const float* w = wv + li * 32;
    float p0 = 0.f, p1 = 0.f, p2 = 0.f, p3 = 0.f;
    const float xs[8] = {x0.x, x0.y, x0.z, x0.w, x1.x, x1.y, x1.z, x1.w};
    #pragma unroll
    for (int j = 0; j < 8; ++j) {
      const float4 wj = *(const float4*)&w[j * 4];
      p0 += xs[j] * wj.x;
      p1 += xs[j] * wj.y;
      p2 += xs[j] * wj.z;
      p3 += xs[j] * wj.w;
    }
    #pragma unroll
    for (int m = 8; m; m >>= 1) {
      p0 += __shfl_xor(p0, m, 64);
      p1 += __shfl_xor(p1, m, 64);
      p2 += __shfl_xor(p2, m, 64);
      p3 += __shfl_xor(p3, m, 64);
    }
    if (li == 0) *(float4*)(o + (size_t)node * 4) = make_float4(p0, p1, p2, p3);
  }
}

// ---------------- p23: fused {per-head CSR offsets} + {bucket -> CSR scatter} ----------
__global__ __launch_bounds__(1024) void p23(const unsigned int* __restrict__ recs,
                                            const int* __restrict__ bucketCursor,
                                            int* __restrict__ off,
                                            int* __restrict__ pt) {
  __shared__ int cur[HPB];
  __shared__ int red[256];
  const int b = blockIdx.x, t = threadIdx.x;
  if (t < 256) red[t] = (t < b) ? bucketCursor[t] : 0;   // b <= 195 < 256
  if (t < HPB) cur[t] = 0;
  __syncthreads();
  for (int st = 128; st; st >>= 1) {                     // bstart = sum of earlier buckets
    if (t < st) red[t] += red[t + st];
    __syncthreads();
  }
  const int bstart = red[0];
  const int cnt = bucketCursor[b];
  const unsigned int* __restrict__ rb = recs + (size_t)b * BCAP;
  for (int i = t; i < cnt; i += 1024)
    atomicAdd(&cur[rb[i] >> 20], 1);
  __syncthreads();
  const int orig = (t < HPB) ? cur[t] : 0;
  for (int st = 1; st < HPB; st <<= 1) {                 // Hillis-Steele inclusive scan
    int v = 0;
    if (t < HPB && t >= st) v = cur[t - st];
    __syncthreads();
    if (t < HPB) cur[t] += v;
    __syncthreads();
  }
  const int h0 = b * HPB;
  if (t < HPB) {
    const int excl = bstart + cur[t] - orig;             // exclusive prefix
    cur[t] = excl;                                       // becomes scatter cursor
    if (h0 + t < N_HEADN) off[h0 + t] = excl;
  }
  if (b == NB - 1 && t == 0) off[N_HEADN] = NEDGE;
  __syncthreads();
  for (int i = t; i < cnt; i += 1024) {
    const unsigned r = rb[i];
    const int pos = atomicAdd(&cur[r >> 20], 1);
    pt[pos] = (int)(r & 0xFFFFFu);                       // ti | et<<17
  }
}

// ---------------- k4: 16-lane groups, CHUNK=32 (2 edges/lane), fp16 + v_fma_mix --------
// R13: measured good (dropped out of top-5, < 78us). No launch-bounds pin (R3 spill).
__global__ __launch_bounds__(256) void k4_agg(const int* __restrict__ off,
                                              const int* __restrict__ pt,
                                              const float* __restrict__ h_l,
                                              const float* __restrict__ h_r,
                                              const float* __restrict__ he,
                                              const __half* __restrict__ h_tail,
                                              float* __restrict__ out) {
  __shared__ __align__(16) float sw[4][4][136];  // 32 slots x4 + pad; group stride 136
  __shared__ int sti[4][4][36];                  // 32 row byte-offsets + pad
  __shared__ __align__(16) float4 she4[8];
  const int wid = threadIdx.x >> 6;
  const int lane = threadIdx.x & 63;
  const int g = lane >> 4, li = lane & 15;
  if (threadIdx.x < 8) she4[threadIdx.x] = ((const float4*)he)[threadIdx.x];
  __syncthreads();                               // only block barrier: she4 visibility
  const int n = blockIdx.x * 16 + wid * 4 + g;   // grid exact: 6250*16
  const int s = off[n], e = off[n + 1];
  const int nch = (e - s + 31) >> 5;
  const float4 hl = *(const float4*)(h_l + (size_t)n * 4);
  const int h = li >> 2;
  const unsigned dby = (unsigned)li * 16u;       // byte offset of lane's 8 dims (fp16)
  float m0 = -1e30f, m1 = -1e30f, m2 = -1e30f, m3 = -1e30f;
  float s0 = 0.f, s1 = 0.f, s2 = 0.f, s3 = 0.f;
  float acc[8];
  #pragma unroll
  for (int d = 0; d < 8; ++d) acc[d] = 0.f;
  float* __restrict__ swg = &sw[wid][g][0];
  int* __restrict__ stig = &sti[wid][g][0];
  const char* __restrict__ htb = (const char*)h_tail;
  for (int c = 0; c < nch; ++c) {
    const int base = s + (c << 5);
    const int rem = min(32, e - base);
    // edge A = base+li, edge B = base+16+li
    float a0 = -1e30f, a1 = -1e30f, a2 = -1e30f, a3 = -1e30f;
    float b0 = -1e30f, b1 = -1e30f, b2 = -1e30f, b3 = -1e30f;
    if (li < rem) {
      const int pk = pt[base + li];
      const unsigned ti = (unsigned)pk & 0x1FFFFu;
      const float4 hr = *(const float4*)((const char*)h_r + (ti << 4));
      const float4 hv = she4[(pk >> 17) & 7];
      a0 = hl.x + hr.x + hv.x;
      a1 = hl.y + hr.y + hv.y;
      a2 = hl.z + hr.z + hv.z;
      a3 = hl.w + hr.w + hv.w;
      a0 = fmaxf(a0, SLOPE * a0);                // leaky relu (slope<1)
      a1 = fmaxf(a1, SLOPE * a1);
      a2 = fmaxf(a2, SLOPE * a2);
      a3 = fmaxf(a3, SLOPE * a3);
      stig[li] = (int)(ti << 8);                 // h_tail row byte offset (256 B/row)
    }
    if (li + 16 < rem) {
      const int pk = pt[base + 16 + li];
      const unsigned ti = (unsigned)pk & 0x1FFFFu;
      const float4 hr = *(const float4*)((const char*)h_r + (ti << 4));
      const float4 hv = she4[(pk >> 17) & 7];
      b0 = hl.x + hr.x + hv.x;
      b1 = hl.y + hr.y + hv.y;
      b2 = hl.z + hr.z + hv.z;
      b3 = hl.w + hr.w + hv.w;
      b0 = fmaxf(b0, SLOPE * b0);
      b1 = fmaxf(b1, SLOPE * b1);
      b2 = fmaxf(b2, SLOPE * b2);
      b3 = fmaxf(b3, SLOPE * b3);
      stig[li + 16] = (int)(ti << 8);
    }
    float c0 = fmaxf(a0, b0), c1 = fmaxf(a1, b1);
    float c2 = fmaxf(a2, b2), c3 = fmaxf(a3, b3);
    #pragma unroll
    for (int msk = 8; msk; msk >>= 1) {          // width-16 max trees (32 edges)
      c0 = fmaxf(c0, __shfl_xor(c0, msk, 64));
      c1 = fmaxf(c1, __shfl_xor(c1, msk, 64));
      c2 = fmaxf(c2, __shfl_xor(c2, msk, 64));
      c3 = fmaxf(c3, __shfl_xor(c3, msk, 64));
    }
    const float nm0 = fmaxf(m0, c0), nm1 = fmaxf(m1, c1);
    const float nm2 = fmaxf(m2, c2), nm3 = fmaxf(m3, c3);
    const float e0 = __expf(m0 - nm0), e1 = __expf(m1 - nm1);
    const float e2 = __expf(m2 - nm2), e3 = __expf(m3 - nm3);
    const float wa0 = __expf(a0 - nm0), wa1 = __expf(a1 - nm1);
    const float wa2 = __expf(a2 - nm2), wa3 = __expf(a3 - nm3);
    const float wb0 = __expf(b0 - nm0), wb1 = __expf(b1 - nm1);
    const float wb2 = __expf(b2 - nm2), wb3 = __expf(b3 - nm3);
    float t0 = wa0 + wb0, t1 = wa1 + wb1;
    float t2 = wa2 + wb2, t3 = wa3 + wb3;
    #pragma unroll
    for (int msk = 8; msk; msk >>= 1) {          // width-16 sum trees (32 edges)
      t0 += __shfl_xor(t0, msk, 64);
      t1 += __shfl_xor(t1, msk, 64);
      t2 += __shfl_xor(t2, msk, 64);
      t3 += __shfl_xor(t3, msk, 64);
    }
    s0 = s0 * e0 + t0; s1 = s1 * e1 + t1;
    s2 = s2 * e2 + t2; s3 = s3 * e3 + t3;
    m0 = nm0; m1 = nm1; m2 = nm2; m3 = nm3;
    *(float4*)&swg[li * 4] = make_float4(wa0, wa1, wa2, wa3);        // 0 for li >= rem
    *(float4*)&swg[(li + 16) * 4] = make_float4(wb0, wb1, wb2, wb3); // 0 for li+16 >= rem
    const float sc = (h == 0) ? e0 : (h == 1) ? e1 : (h == 2) ? e2 : e3;
    #pragma unroll
    for (int d = 0; d < 8; ++d) acc[d] *= sc;
    __builtin_amdgcn_wave_barrier();
    int j = 0;
    for (; j + 4 <= rem; j += 4) {
      const int o0 = stig[j], o1 = stig[j + 1], o2 = stig[j + 2], o3 = stig[j + 3];
      const float q0 = swg[(j + 0) * 4 + h];
      const float q1 = swg[(j + 1) * 4 + h];
      const float q2 = swg[(j + 2) * 4 + h];
      const float q3 = swg[(j + 3) * 4 + h];
      const uint4 v0 = *(const uint4*)(htb + (unsigned)o0 + dby);
      const uint4 v1 = *(const uint4*)(htb + (unsigned)o1 + dby);
      const uint4 v2 = *(const uint4*)(htb + (unsigned)o2 + dby);
      const uint4 v3 = *(const uint4*)(htb + (unsigned)o3 + dby);
      FMA_MIX_LO(acc[0], v0.x, q0); FMA_MIX_HI(acc[1], v0.x, q0);
      FMA_MIX_LO(acc[2], v0.y, q0); FMA_MIX_HI(acc[3], v0.y, q0);
      FMA_MIX_LO(acc[4], v0.z, q0); FMA_MIX_HI(acc[5], v0.z, q0);
      FMA_MIX_LO(acc[6], v0.w, q0); FMA_MIX_HI(acc[7], v0.w, q0);
      FMA_MIX_LO(acc[0], v1.x, q1); FMA_MIX_HI(acc[1], v1.x, q1);
      FMA_MIX_LO(acc[2], v1.y, q1); FMA_MIX_HI(acc[3], v1.y, q1);
      FMA_MIX_LO(acc[4], v1.z, q1); FMA_MIX_HI(acc[5], v1.z, q1);
      FMA_MIX_LO(acc[6], v1.w, q1); FMA_MIX_HI(acc[7], v1.w, q1);
      FMA_MIX_LO(acc[0], v2.x, q2); FMA_MIX_HI(acc[1], v2.x, q2);
      FMA_MIX_LO(acc[2], v2.y, q2); FMA_MIX_HI(acc[3], v2.y, q2);
      FMA_MIX_LO(acc[4], v2.z, q2); FMA_MIX_HI(acc[5], v2.z, q2);
      FMA_MIX_LO(acc[6], v2.w, q2); FMA_MIX_HI(acc[7], v2.w, q2);
      FMA_MIX_LO(acc[0], v3.x, q3); FMA_MIX_HI(acc[1], v3.x, q3);
      FMA_MIX_LO(acc[2], v3.y, q3); FMA_MIX_HI(acc[3], v3.y, q3);
      FMA_MIX_LO(acc[4], v3.z, q3); FMA_MIX_HI(acc[5], v3.z, q3);
      FMA_MIX_LO(acc[6], v3.w, q3); FMA_MIX_HI(acc[7], v3.w, q3);
    }
    for (; j < rem; ++j) {
      const int o = stig[j];
      const float q = swg[j * 4 + h];
      const uint4 v = *(const uint4*)(htb + (unsigned)o + dby);
      FMA_MIX_LO(acc[0], v.x, q); FMA_MIX_HI(acc[1], v.x, q);
      FMA_MIX_LO(acc[2], v.y, q); FMA_MIX_HI(acc[3], v.y, q);
      FMA_MIX_LO(acc[4], v.z, q); FMA_MIX_HI(acc[5], v.z, q);
      FMA_MIX_LO(acc[6], v.w, q); FMA_MIX_HI(acc[7], v.w, q);
    }
    __builtin_amdgcn_wave_barrier();
  }
  const float denom = (h == 0) ? s0 : (h == 1) ? s1 : (h == 2) ? s2 : s3;
  const float inv = denom > 0.f ? 1.f / denom : 0.f;
  float o[8];
  #pragma unroll
  for (int d = 0; d < 8; ++d) {
    const float v = acc[d] * inv;
    o[d] = v > 0.f ? v : expm1f(v);
  }
  float* op = out + (size_t)n * 128 + li * 8;
  *(float4*)op = make_float4(o[0], o[1], o[2], o[3]);
  *(float4*)(op + 4) = make_float4(o[4], o[5], o[6], o[7]);
}

extern "C" void kernel_launch(void* const* d_in, const int* in_sizes, int n_in,
                              void* d_out, int out_size, void* d_ws, size_t ws_size,
                              hipStream_t stream) {
  const float* head = (const float*)d_in[0];
  const float* tail = (const float*)d_in[1];
  const int* elist  = (const int*)d_in[2];
  const int* etype  = (const int*)d_in[3];
  const float* W    = (const float*)d_in[4];
  const float* W_e  = (const float*)d_in[5];
  const float* a_l  = (const float*)d_in[6];
  const float* a_r  = (const float*)d_in[7];
  const float* a_e  = (const float*)d_in[8];
  const float* emb  = (const float*)d_in[9];
  const int* head_ind = elist;
  const int* tail_ind = elist + NEDGE;
  (void)in_sizes; (void)n_in; (void)out_size; (void)ws_size;

  char* p = (char*)d_ws;
  size_t o = 0;
  auto carve = [&](size_t bytes) {
    char* r = p + o;
    o += (bytes + 255) & ~(size_t)255;
    return r;
  };
  // total ~42.6 MB
  __half* h_tail = (__half*)carve((size_t)N_TAILN * 128 * 2);                   // 25.6 MB
  int*   pt     = (int*)   carve((size_t)NEDGE * 4);                            // 6.4 MB
  unsigned int* recs = (unsigned int*)carve((size_t)NB * BCAP * 4);             // 7.2 MB
  float* h_l    = (float*) carve((size_t)N_HEADN * 4 * 4);                      // 1.6 MB
  float* h_r    = (float*) carve((size_t)N_TAILN * 4 * 4);                      // 1.6 MB
  int*   off    = (int*)   carve((size_t)(N_HEADN + 1) * 4);                    // 0.4 MB
  int*   bucketCursor = (int*)carve(NB * 4);
  float* wl     = (float*) carve(128 * 4 * 4);
  float* he     = (float*) carve(8 * 4 * 4);
  __hip_bfloat16* WbT = (__hip_bfloat16*)carve(16384 * 2);                      // 32 KB

  hipMemsetAsync(bucketCursor, 0, NB * sizeof(int), stream);
  k0m<<<16, 256, 0, stream>>>(W, W_e, a_l, a_e, emb, WbT, wl, he);
  fusedA<<<FB_K2 + FB_P1 + FB_K1, 256, 0, stream>>>(
      tail, WbT, a_r, h_tail, h_r,
      head_ind, tail_ind, etype, bucketCursor, recs,
      head, wl, h_l);
  p23<<<NB, 1024, 0, stream>>>(recs, bucketCursor, off, pt);
  k4_agg<<<N_HEADN / 16, 256, 0, stream>>>(off, pt, h_l, h_r, he, h_tail, (float*)d_out);
}